// Round 10
// baseline (2715.731 us; speedup 1.0000x reference)
//
#include <hip/hip_runtime.h>
#include <math.h>

// Problem constants (reference: B,T,V,E,H = 32,512,32000,300,256)
#define BB 32
#define TT_LEN 512
#define EE 300
#define KPAD 320         // EE padded to multiple of 32 for MFMA K
#define HH 256
#define G4 1024          // 4*H
#define CMAX 155         // int(round(0.3*512))+1
#define TRANS_T 10.0f    // TRANSITION/TEMP
#define NEGF -1.0e9f
#define INV_TEMP 100.0f  // 1/TEMP
#define AST_STRIDE 160   // slot-2 accesses predicated l<27

#define NCH 32           // all 32 uint4 weight chunks register-resident

typedef _Float16 half2v __attribute__((ext_vector_type(2)));
typedef _Float16 half8 __attribute__((ext_vector_type(8)));
typedef float f32x4 __attribute__((ext_vector_type(4)));

__device__ __forceinline__ float la(float x, float y) {
  float m = fmaxf(x, y);
  float d = fminf(x, y) - m;
  return m + __logf(1.0f + __expf(d));
}

__device__ __forceinline__ float sigm(float x) {
  return 1.0f / (1.0f + __expf(-x));
}

__device__ __forceinline__ float dot2acc(unsigned int wd, unsigned int hd, float acc) {
#if __has_builtin(__builtin_amdgcn_fdot2)
  return __builtin_amdgcn_fdot2(__builtin_bit_cast(half2v, wd),
                                __builtin_bit_cast(half2v, hd), acc, false);
#else
  half2v a = __builtin_bit_cast(half2v, wd);
  half2v b = __builtin_bit_cast(half2v, hd);
  return acc + (float)a.x * (float)b.x + (float)a.y * (float)b.y;
#endif
}

__device__ __forceinline__ unsigned int packh(float a, float b) {
  half2v hp;
  hp.x = (_Float16)a;
  hp.y = (_Float16)b;
  return __builtin_bit_cast(unsigned int, hp);
}

// ---------------- K0: weight prep ------------------------------------------
// wi_t: f16 [dir][j'][k], j' = u*4+g, k padded to KPAD (zeros k>=300).
// wall_h: ALL wh chunks, packed f16 dwords (dword = k-pair (2k,2k+1) of gate
//   column j): idx ((dir*NCH + g)*1024 + j)*4 + d, k0 = 8g+2d. Same total
//   bytes as old wlds_h+wstr_h (8+24=32 chunks) -> workspace layout intact.
__global__ void prep_weights(const float* wi_f, const float* wi_b,
                             const float* wh_f, const float* wh_b,
                             const float* b_f, const float* b_b,
                             _Float16* wi_t, float* b_p,
                             unsigned int* wall_h) {
  int idx = blockIdx.x * blockDim.x + threadIdx.x;
  int stride = gridDim.x * blockDim.x;
  // wi transpose: 2 * 1024 * KPAD f16
  for (int i = idx; i < 2 * G4 * KPAD; i += stride) {
    int dir = i / (G4 * KPAD);
    int r = i % (G4 * KPAD);
    int j = r / KPAD;
    int k = r % KPAD;
    int g = j & 3, u = j >> 2;
    const float* src = dir ? wi_b : wi_f;
    wi_t[i] = (k < EE) ? (_Float16)src[(size_t)k * G4 + g * HH + u] : (_Float16)0.0f;
  }
  // wh chunks: 2 * NCH * 1024 * 4 dwords
  for (int i = idx; i < 2 * NCH * 4096; i += stride) {
    int dir = i / (NCH * 4096);
    int r = i % (NCH * 4096);
    int gch = r / 4096;
    int r2 = r % 4096;
    int j = r2 >> 2, d = r2 & 3;
    int g = j & 3, u = j >> 2;
    int k0 = 8 * gch + 2 * d;
    const float* src = dir ? wh_b : wh_f;
    wall_h[i] = packh(src[k0 * G4 + g * HH + u], src[(k0 + 1) * G4 + g * HH + u]);
  }
  for (int i = idx; i < 2 * G4; i += stride) {
    int dir = i / G4;
    int j = i % G4;
    int g = j & 3, u = j >> 2;
    const float* src = dir ? b_b : b_f;
    b_p[i] = src[g * HH + u];
  }
}

// ---------------- K_emb: gather embedding rows -> f16 dense (B*T, KPAD) ----
__global__ void gather_emb(const int* x, const float* embed, _Float16* emb_h) {
  int row = blockIdx.x;
  int v = x[row];
  const float* src = embed + (size_t)v * EE;
  _Float16* dst = emb_h + (size_t)row * KPAD;
  for (int k = threadIdx.x; k < KPAD; k += blockDim.x)
    dst[k] = (k < EE) ? (_Float16)src[k] : (_Float16)0.0f;
}

// ---------------- K1: xg = emb_h @ wi_t^T + b_p  (f16 MFMA) ----------------
__global__ __launch_bounds__(256) void xg_mfma(
    const _Float16* __restrict__ emb_h, const _Float16* __restrict__ wi_t,
    const float* __restrict__ b_p, float* __restrict__ xg) {
  int dir = blockIdx.z;
  int n0 = blockIdx.x * 64;
  int m0 = blockIdx.y * 64;
  int wave = threadIdx.x >> 6;
  int lane = threadIdx.x & 63;
  int l15 = lane & 15, quad = lane >> 4;

  const _Float16* arow = emb_h + (size_t)(m0 + wave * 16 + l15) * KPAD + quad * 8;
  const _Float16* bbase =
      wi_t + ((size_t)dir * G4 + n0 + l15) * KPAD + quad * 8;

  f32x4 acc[4];
#pragma unroll
  for (int nt = 0; nt < 4; ++nt) acc[nt] = (f32x4){0.f, 0.f, 0.f, 0.f};

#pragma unroll
  for (int kk = 0; kk < KPAD / 32; ++kk) {
    half8 a = *(const half8*)(arow + kk * 32);
#pragma unroll
    for (int nt = 0; nt < 4; ++nt) {
      half8 b = *(const half8*)(bbase + (size_t)nt * 16 * KPAD + kk * 32);
      acc[nt] = __builtin_amdgcn_mfma_f32_16x16x32_f16(a, b, acc[nt], 0, 0, 0);
    }
  }
#pragma unroll
  for (int nt = 0; nt < 4; ++nt) {
    int n = n0 + nt * 16 + l15;
    float bias = b_p[dir * G4 + n];
#pragma unroll
    for (int r = 0; r < 4; ++r) {
      int m = m0 + wave * 16 + quad * 4 + r;
      xg[((size_t)dir * (BB * TT_LEN) + m) * G4 + n] = acc[nt][r] + bias;
    }
  }
}

// ---------------- K2: LSTM recurrence, ALL weights register-resident -------
// 64 blocks (dir,b), 512 threads (8 waves, pinned 2/SIMD). Thread t owns gate
// columns t and t+512; its 256 weight dwords (2x32 uint4) live in VGPR/AGPR
// (round-8 evidence: 192 AGPR-dwords resident, no spill). LDS per step is
// ONLY the h broadcast: 32 wave-uniform ds_read_b128 (broadcast, no
// conflict) -> ~256 LDS instr/CU/step vs round-8's 384 (which included 128
// per-lane weight b128 reads -- the measured bottleneck).
__global__ __attribute__((amdgpu_flat_work_group_size(512, 512),
                          amdgpu_waves_per_eu(2, 2))) void lstm_v4(
    const float* __restrict__ xg, const uint4* __restrict__ wall,
    const float* __restrict__ w_out, float* __restrict__ scores_part) {
  int bid = blockIdx.x;            // 64 blocks: dir*32 + b
  int dir = bid >> 5, b = bid & 31;
  int t = threadIdx.x;             // 0..511
  int lane = t & 63, wid = t >> 6;

  __shared__ uint4 hpk4[32];             // 256 h as 128 packed-f16 dwords
  __shared__ float gates[1024];
  __shared__ float wpart[2][4];

  // load all weights into registers (coalesced per wave)
  const uint4* wsb = wall + (size_t)dir * (NCH * 1024);
  uint4 wr0[NCH], wr1[NCH];
#pragma unroll
  for (int g = 0; g < NCH; ++g) {
    wr0[g] = wsb[g * 1024 + t];
    wr1[g] = wsb[g * 1024 + 512 + t];
  }
  if (t < 32) hpk4[t] = uint4{0, 0, 0, 0};
  __syncthreads();

  const float* xgbase =
      xg + (size_t)(dir * (BB * TT_LEN) + b * TT_LEN) * G4 + t;
  float wo = (t < HH) ? w_out[dir * HH + t] : 0.0f;
  float cstate = 0.0f;

  int t0 = dir ? (TT_LEN - 1) : 0;
  float xgn0 = xgbase[(size_t)t0 * G4];
  float xgn1 = xgbase[(size_t)t0 * G4 + 512];

#pragma unroll 1
  for (int s = 0; s < TT_LEN; ++s) {
    int tt = dir ? (TT_LEN - 1 - s) : s;
    float acc0a = xgn0, acc1a = xgn1;
    float acc0b = 0.0f, acc1b = 0.0f;
    if (s + 1 < TT_LEN) {
      int t2 = dir ? (TT_LEN - 2 - s) : (s + 1);
      xgn0 = xgbase[(size_t)t2 * G4];
      xgn1 = xgbase[(size_t)t2 * G4 + 512];
    }
#pragma unroll
    for (int c = 0; c < NCH; ++c) {
      uint4 h = hpk4[c];     // wave-uniform address -> broadcast read
      uint4 w0 = wr0[c];
      uint4 w1 = wr1[c];
      if (c < 16) {
        acc0a = dot2acc(w0.x, h.x, acc0a);
        acc0a = dot2acc(w0.y, h.y, acc0a);
        acc0a = dot2acc(w0.z, h.z, acc0a);
        acc0a = dot2acc(w0.w, h.w, acc0a);
        acc1a = dot2acc(w1.x, h.x, acc1a);
        acc1a = dot2acc(w1.y, h.y, acc1a);
        acc1a = dot2acc(w1.z, h.z, acc1a);
        acc1a = dot2acc(w1.w, h.w, acc1a);
      } else {
        acc0b = dot2acc(w0.x, h.x, acc0b);
        acc0b = dot2acc(w0.y, h.y, acc0b);
        acc0b = dot2acc(w0.z, h.z, acc0b);
        acc0b = dot2acc(w0.w, h.w, acc0b);
        acc1b = dot2acc(w1.x, h.x, acc1b);
        acc1b = dot2acc(w1.y, h.y, acc1b);
        acc1b = dot2acc(w1.z, h.z, acc1b);
        acc1b = dot2acc(w1.w, h.w, acc1b);
      }
    }
    gates[t] = acc0a + acc0b;
    gates[512 + t] = acc1a + acc1b;
    __syncthreads();

    if (t < HH) {
      float4 g4 = ((const float4*)gates)[t];
      float ig = sigm(g4.x);
      float fg = sigm(g4.y);
      float gg = tanhf(g4.z);
      float og = sigm(g4.w);
      cstate = fg * cstate + ig * gg;
      float h = og * tanhf(cstate);
      float prod = h * wo;
#pragma unroll
      for (int off = 32; off > 0; off >>= 1) prod += __shfl_down(prod, off, 64);
      if (lane == 0) wpart[s & 1][wid] = prod;
      float hn = __shfl_down(h, 1, 64);
      if (!(t & 1)) ((unsigned int*)hpk4)[t >> 1] = packh(h, hn);
    }
    __syncthreads();
    if (t == 0) {
      scores_part[(size_t)(dir * BB + b) * TT_LEN + tt] =
          wpart[s & 1][0] + wpart[s & 1][1] + wpart[s & 1][2] + wpart[s & 1][3];
    }
  }
}

// ---------------- K4: CRF forward-backward, single wave per batch ----------
__global__ __launch_bounds__(64) void dp2(const float* __restrict__ scores_part,
                                          const float* __restrict__ b_out,
                                          float* __restrict__ ast_g,
                                          float* __restrict__ out) {
  int b = blockIdx.x;
  int l = threadIdx.x;  // 0..63
  const float* spf = scores_part + (size_t)b * TT_LEN;
  const float* spb = scores_part + (size_t)(BB + b) * TT_LEN;
  float bo = b_out[0];
  float* ast = ast_g + (size_t)b * TT_LEN * AST_STRIDE;

  float ur[8];
#pragma unroll
  for (int i = 0; i < 8; ++i)
    ur[i] = (spf[i * 64 + l] + spb[i * 64 + l] + bo) * INV_TEMP;

  int lm1 = (l + 63) & 63;
  int lp1 = (l + 1) & 63;

  float a0[3], a1[3];
  float u00 = __shfl(ur[0], 0, 64);
  a0[0] = (l == 1) ? (u00 + TRANS_T) : NEGF;
  a0[1] = NEGF;
  a0[2] = NEGF;
  a1[0] = (l == 0) ? 0.0f : NEGF;
  a1[1] = NEGF;
  a1[2] = NEGF;
  ast[l] = a0[0];
  ast[64 + l] = a0[1];
  if (l < 27) ast[128 + l] = a0[2];

  // ---- forward t = 1..511 ----
#pragma unroll
  for (int ch = 0; ch < 8; ++ch) {
    float uc = ur[ch];
#pragma unroll 1
    for (int tt = (ch == 0 ? 1 : 0); tt < 64; ++tt) {
      int t = ch * 64 + tt;
      float u0t = __shfl(uc, tt, 64);
      float w0a = __shfl(a0[0], lm1, 64);
      float w1a = __shfl(a0[1], lm1, 64);
      float w2a = __shfl(a0[2], lm1, 64);
      float w0b = __shfl(a1[0], lm1, 64);
      float w1b = __shfl(a1[1], lm1, 64);
      float w2b = __shfl(a1[2], lm1, 64);
      float p0a = (l == 0) ? NEGF : w0a;
      float p1a = (l == 0) ? w0a : w1a;
      float p2a = (l == 0) ? w1a : w2a;
      float p0b = (l == 0) ? NEGF : w0b;
      float p1b = (l == 0) ? w0b : w1b;
      float p2b = (l == 0) ? w1b : w2b;
      float n00 = u0t + la(p0a + TRANS_T, p0b);
      float n01 = u0t + la(p1a + TRANS_T, p1b);
      float n02 = u0t + la(p2a + TRANS_T, p2b);
      float n10 = la(a0[0], a1[0]);
      float n11 = la(a0[1], a1[1]);
      float n12 = la(a0[2], a1[2]);
      a0[0] = n00;
      a0[1] = n01;
      a0[2] = (l < 27) ? n02 : NEGF;
      a1[0] = n10;
      a1[1] = n11;
      a1[2] = (l < 27) ? n12 : NEGF;
      float* astr = ast + (size_t)t * AST_STRIDE;
      astr[l] = a0[0];
      astr[64 + l] = a0[1];
      if (l < 27) astr[128 + l] = a0[2];
    }
  }

  // ---- logZ ----
  float f00 = a0[0] + TRANS_T, f01 = a0[1] + TRANS_T, f02 = a0[2] + TRANS_T;
  float m = fmaxf(fmaxf(fmaxf(f00, f01), fmaxf(f02, a1[0])), fmaxf(a1[1], a1[2]));
#pragma unroll
  for (int off = 32; off > 0; off >>= 1) m = fmaxf(m, __shfl_xor(m, off, 64));
  float es = __expf(f00 - m) + __expf(f01 - m) + __expf(f02 - m) +
             __expf(a1[0] - m) + __expf(a1[1] - m) + __expf(a1[2] - m);
#pragma unroll
  for (int off = 32; off > 0; off >>= 1) es += __shfl_xor(es, off, 64);
  float lz = m + __logf(es);

  // ---- backward init (t = 511) ----
  float b0[3], b1[3];
  b0[0] = TRANS_T;
  b0[1] = TRANS_T;
  b0[2] = (l < 27) ? TRANS_T : NEGF;
  b1[0] = 0.0f;
  b1[1] = 0.0f;
  b1[2] = (l < 27) ? 0.0f : NEGF;
  {
    float ts = __expf(a0[0] + TRANS_T - lz) + __expf(a0[1] + TRANS_T - lz) +
               ((l < 27) ? __expf(a0[2] + TRANS_T - lz) : 0.0f);
#pragma unroll
    for (int off = 32; off > 0; off >>= 1) ts += __shfl_xor(ts, off, 64);
    if (l == 0) out[b * TT_LEN + (TT_LEN - 1)] = ts;
  }

  float nr0 = ast[(size_t)510 * AST_STRIDE + l];
  float nr1 = ast[(size_t)510 * AST_STRIDE + 64 + l];
  float nr2 = (l < 27) ? ast[(size_t)510 * AST_STRIDE + 128 + l] : NEGF;

  // ---- backward t = 511..1 ----
#pragma unroll
  for (int ch = 7; ch >= 0; --ch) {
    float uc = ur[ch];
#pragma unroll 1
    for (int tt = 63; tt >= (ch == 0 ? 1 : 0); --tt) {
      int t = ch * 64 + tt;
      float u0t = __shfl(uc, tt, 64);
      float c0 = nr0, c1 = nr1, c2 = nr2;
      if (t >= 2) {
        const float* astr = ast + (size_t)(t - 2) * AST_STRIDE;
        nr0 = astr[l];
        nr1 = astr[64 + l];
        nr2 = (l < 27) ? astr[128 + l] : NEGF;
      }
      float w0 = __shfl(b0[0], lp1, 64);
      float w1 = __shfl(b0[1], lp1, 64);
      float w2 = __shfl(b0[2], lp1, 64);
      float x2 = (l == 63) ? NEGF : w2;
      float x1 = (l == 63) ? w2 : w1;
      float x0 = (l == 63) ? w1 : w0;
      float nb00 = la(u0t + TRANS_T + x0, b1[0]);
      float nb01 = la(u0t + TRANS_T + x1, b1[1]);
      float nb02 = la(u0t + TRANS_T + x2, b1[2]);
      float nb10 = la(u0t + x0, b1[0]);
      float nb11 = la(u0t + x1, b1[1]);
      float nb12 = la(u0t + x2, b1[2]);
      float tm = __expf(c0 + nb00 - lz) + __expf(c1 + nb01 - lz) +
                 ((l < 27) ? __expf(c2 + nb02 - lz) : 0.0f);
#pragma unroll
      for (int off = 32; off > 0; off >>= 1) tm += __shfl_xor(tm, off, 64);
      if (l == 0) out[b * TT_LEN + (t - 1)] = tm;
      b0[0] = nb00;
      b0[1] = nb01;
      b0[2] = (l < 27) ? nb02 : NEGF;
      b1[0] = nb10;
      b1[1] = nb11;
      b1[2] = (l < 27) ? nb12 : NEGF;
    }
  }
}

// ---------------------------------------------------------------------------
extern "C" void kernel_launch(void* const* d_in, const int* in_sizes, int n_in,
                              void* d_out, int out_size, void* d_ws, size_t ws_size,
                              hipStream_t stream) {
  const int* x = (const int*)d_in[0];
  const float* embed = (const float*)d_in[3];
  const float* wi_f = (const float*)d_in[4];
  const float* wh_f = (const float*)d_in[5];
  const float* bf = (const float*)d_in[6];
  const float* wi_b = (const float*)d_in[7];
  const float* wh_b = (const float*)d_in[8];
  const float* bbias = (const float*)d_in[9];
  const float* w_out = (const float*)d_in[10];
  const float* b_out = (const float*)d_in[11];

  float* ws = (float*)d_ws;
  float* b_p = ws;                                      // 2*1024 f32
  unsigned int* wall_h = (unsigned int*)(b_p + 2 * G4); // 2*32*4096 dwords
  _Float16* wi_t = (_Float16*)(wall_h + 2 * NCH * 4096);  // 2*1024*320 f16
  _Float16* emb_h = wi_t + (size_t)2 * G4 * KPAD;       // 16384*320 f16
  float* xg = (float*)(emb_h + (size_t)BB * TT_LEN * KPAD);  // 2*16384*1024 f32
  float* scores_part = xg + (size_t)2 * BB * TT_LEN * G4;    // 2*16384
  float* u0_unused = scores_part + 2 * BB * TT_LEN;     // 16384 (layout keep)
  float* ast_g = u0_unused + BB * TT_LEN;               // 32*512*160 f32
  float* outp = (float*)d_out;

  prep_weights<<<256, 256, 0, stream>>>(wi_f, wi_b, wh_f, wh_b, bf, bbias,
                                        wi_t, b_p, wall_h);
  gather_emb<<<BB * TT_LEN, 256, 0, stream>>>(x, embed, emb_h);
  dim3 g1(G4 / 64, (BB * TT_LEN) / 64, 2);
  xg_mfma<<<g1, 256, 0, stream>>>(emb_h, wi_t, b_p, xg);
  lstm_v4<<<64, 512, 0, stream>>>(xg, (const uint4*)wall_h, w_out, scores_part);
  dp2<<<BB, 64, 0, stream>>>(scores_part, b_out, ast_g, outp);
}

// Round 11
// 2001.838 us; speedup vs baseline: 1.3566x; 1.3566x over previous
//
#include <hip/hip_runtime.h>
#include <math.h>

// Problem constants (reference: B,T,V,E,H = 32,512,32000,300,256)
#define BB 32
#define TT_LEN 512
#define EE 300
#define KPAD 320         // EE padded to multiple of 32 for MFMA K
#define HH 256
#define G4 1024          // 4*H
#define CMAX 155         // int(round(0.3*512))+1
#define TRANS_T 10.0f    // TRANSITION/TEMP
#define NEGF -1.0e9f
#define INV_TEMP 100.0f  // 1/TEMP
#define AST_STRIDE 160   // slot-2 accesses predicated l<27

// lstm weight split (round-8 proven, no spill): LDS part = 8 uint4-chunks
// (k<64, 128 KB), register part = 24 uint4-chunks (k=64..255, 192 dwords).
#define NCH_L2 8
#define NREG 24

typedef _Float16 half2v __attribute__((ext_vector_type(2)));
typedef _Float16 half8 __attribute__((ext_vector_type(8)));
typedef float f32x4 __attribute__((ext_vector_type(4)));

__device__ __forceinline__ float la(float x, float y) {
  float m = fmaxf(x, y);
  float d = fminf(x, y) - m;
  return m + __logf(1.0f + __expf(d));
}

__device__ __forceinline__ float sigm(float x) {
  return 1.0f / (1.0f + __expf(-x));
}

__device__ __forceinline__ float dot2acc(unsigned int wd, unsigned int hd, float acc) {
#if __has_builtin(__builtin_amdgcn_fdot2)
  return __builtin_amdgcn_fdot2(__builtin_bit_cast(half2v, wd),
                                __builtin_bit_cast(half2v, hd), acc, false);
#else
  half2v a = __builtin_bit_cast(half2v, wd);
  half2v b = __builtin_bit_cast(half2v, hd);
  return acc + (float)a.x * (float)b.x + (float)a.y * (float)b.y;
#endif
}

__device__ __forceinline__ unsigned int packh(float a, float b) {
  half2v hp;
  hp.x = (_Float16)a;
  hp.y = (_Float16)b;
  return __builtin_bit_cast(unsigned int, hp);
}

// ---------------- K0: weight prep (round-8 proven version) -----------------
// wi_t: f16 [dir][j'][k], j' = u*4+g, k padded to KPAD (zeros k>=300).
// wh packed f16 dwords (dword = k-pair (2k,2k+1) of gate column j):
//   LDS part  wlds_h: idx ((dir*NCH_L2 + c)*1024 + j)*4 + d, k0 = 8c+2d
//   reg part  wstr_h: idx ((dir*NREG + g)*1024 + j)*4 + d, k0 = 64+8g+2d
__global__ void prep_weights(const float* wi_f, const float* wi_b,
                             const float* wh_f, const float* wh_b,
                             const float* b_f, const float* b_b,
                             _Float16* wi_t, float* b_p,
                             unsigned int* wlds_h, unsigned int* wstr_h) {
  int idx = blockIdx.x * blockDim.x + threadIdx.x;
  int stride = gridDim.x * blockDim.x;
  for (int i = idx; i < 2 * G4 * KPAD; i += stride) {
    int dir = i / (G4 * KPAD);
    int r = i % (G4 * KPAD);
    int j = r / KPAD;
    int k = r % KPAD;
    int g = j & 3, u = j >> 2;
    const float* src = dir ? wi_b : wi_f;
    wi_t[i] = (k < EE) ? (_Float16)src[(size_t)k * G4 + g * HH + u] : (_Float16)0.0f;
  }
  for (int i = idx; i < 2 * NCH_L2 * 4096; i += stride) {
    int dir = i / (NCH_L2 * 4096);
    int r = i % (NCH_L2 * 4096);
    int c = r / 4096;
    int r2 = r % 4096;
    int j = r2 >> 2, d = r2 & 3;
    int g = j & 3, u = j >> 2;
    int k0 = 8 * c + 2 * d;
    const float* src = dir ? wh_b : wh_f;
    wlds_h[i] = packh(src[k0 * G4 + g * HH + u], src[(k0 + 1) * G4 + g * HH + u]);
  }
  for (int i = idx; i < 2 * NREG * 4096; i += stride) {
    int dir = i / (NREG * 4096);
    int r = i % (NREG * 4096);
    int gch = r / 4096;
    int r2 = r % 4096;
    int j = r2 >> 2, d = r2 & 3;
    int g = j & 3, u = j >> 2;
    int k0 = 64 + 8 * gch + 2 * d;
    const float* src = dir ? wh_b : wh_f;
    wstr_h[i] = packh(src[k0 * G4 + g * HH + u], src[(k0 + 1) * G4 + g * HH + u]);
  }
  for (int i = idx; i < 2 * G4; i += stride) {
    int dir = i / G4;
    int j = i % G4;
    int g = j & 3, u = j >> 2;
    const float* src = dir ? b_b : b_f;
    b_p[i] = src[g * HH + u];
  }
}

// ---------------- K_emb: gather embedding rows -> f16 dense (B*T, KPAD) ----
__global__ void gather_emb(const int* x, const float* embed, _Float16* emb_h) {
  int row = blockIdx.x;
  int v = x[row];
  const float* src = embed + (size_t)v * EE;
  _Float16* dst = emb_h + (size_t)row * KPAD;
  for (int k = threadIdx.x; k < KPAD; k += blockDim.x)
    dst[k] = (k < EE) ? (_Float16)src[k] : (_Float16)0.0f;
}

// ---------------- K1: xg = emb_h @ wi_t^T + b_p  (f16 MFMA) ----------------
__global__ __launch_bounds__(256) void xg_mfma(
    const _Float16* __restrict__ emb_h, const _Float16* __restrict__ wi_t,
    const float* __restrict__ b_p, float* __restrict__ xg) {
  int dir = blockIdx.z;
  int n0 = blockIdx.x * 64;
  int m0 = blockIdx.y * 64;
  int wave = threadIdx.x >> 6;
  int lane = threadIdx.x & 63;
  int l15 = lane & 15, quad = lane >> 4;

  const _Float16* arow = emb_h + (size_t)(m0 + wave * 16 + l15) * KPAD + quad * 8;
  const _Float16* bbase =
      wi_t + ((size_t)dir * G4 + n0 + l15) * KPAD + quad * 8;

  f32x4 acc[4];
#pragma unroll
  for (int nt = 0; nt < 4; ++nt) acc[nt] = (f32x4){0.f, 0.f, 0.f, 0.f};

#pragma unroll
  for (int kk = 0; kk < KPAD / 32; ++kk) {
    half8 a = *(const half8*)(arow + kk * 32);
#pragma unroll
    for (int nt = 0; nt < 4; ++nt) {
      half8 b = *(const half8*)(bbase + (size_t)nt * 16 * KPAD + kk * 32);
      acc[nt] = __builtin_amdgcn_mfma_f32_16x16x32_f16(a, b, acc[nt], 0, 0, 0);
    }
  }
#pragma unroll
  for (int nt = 0; nt < 4; ++nt) {
    int n = n0 + nt * 16 + l15;
    float bias = b_p[dir * G4 + n];
#pragma unroll
    for (int r = 0; r < 4; ++r) {
      int m = m0 + wave * 16 + quad * 4 + r;
      xg[((size_t)dir * (BB * TT_LEN) + m) * G4 + n] = acc[nt][r] + bias;
    }
  }
}

// ---------------- K2: LSTM, single-barrier step, in-wave activation --------
// 64 blocks (dir,b), 512 threads (8 waves). Thread t owns gate cols t, t+512.
// Gate interleave j'=4u+g means unit u's 4 gates sit in 4 ADJACENT LANES of
// one wave -> gather via 3 shfl_down, activations computed in-wave (no gates
// array, no second barrier). h published to parity-double-buffered hpk (the
// dbuf makes one barrier/step sufficient: step s reads buf[s&1], writes
// buf[(s+1)&1] -- never the buffer any wave still reads). Weights: round-8
// split (8 chunks LDS + 24 chunks reg, spill-free at 2 waves/SIMD).
// Score partial: stride-4 shuffle reduce -> wpart[par][wave]; t==0 sums the
// previous step's 8 slots after the barrier (safe: overwrite of wpart[par]
// happens 2 barriers after the read).
__global__ __launch_bounds__(512, 2) void lstm_v5(
    const float* __restrict__ xg, const unsigned int* __restrict__ wlds_h,
    const uint4* __restrict__ wstr, const float* __restrict__ w_out,
    float* __restrict__ scores_part) {
  int bid = blockIdx.x;            // 64 blocks: dir*32 + b
  int dir = bid >> 5, b = bid & 31;
  int t = threadIdx.x;             // 0..511
  int lane = t & 63, w = t >> 6;

  __shared__ uint4 wlds[NCH_L2 * 1024];  // 128 KB
  __shared__ uint4 hpk4[2][32];          // parity-dbuf h (128 dwords each)
  __shared__ float wpart[2][8];

  const uint4* wsrcl = (const uint4*)wlds_h + (size_t)dir * (NCH_L2 * 1024);
  for (int i = t; i < NCH_L2 * 1024; i += 512) wlds[i] = wsrcl[i];
  const uint4* wsb = wstr + (size_t)dir * (NREG * 1024);
  uint4 wr0[NREG], wr1[NREG];
#pragma unroll
  for (int g = 0; g < NREG; ++g) {
    wr0[g] = wsb[g * 1024 + t];
    wr1[g] = wsb[g * 1024 + t + 512];
  }
  if (t < 32) hpk4[0][t] = uint4{0, 0, 0, 0};
  __syncthreads();

  const float* xgbase =
      xg + (size_t)(dir * (BB * TT_LEN) + b * TT_LEN) * G4 + t;
  // this lane's two units (valid data at lanes with lane%4==0)
  int q = lane >> 2;
  int U0 = 16 * w + q;             // 0..127
  float wo0 = w_out[dir * HH + U0];
  float wo1 = w_out[dir * HH + 128 + U0];
  float cs0 = 0.0f, cs1 = 0.0f;
  float* scrow = scores_part + (size_t)(dir * BB + b) * TT_LEN;

  int t0 = dir ? (TT_LEN - 1) : 0;
  float xgn0 = xgbase[(size_t)t0 * G4];
  float xgn1 = xgbase[(size_t)t0 * G4 + 512];

#pragma unroll 1
  for (int s = 0; s < TT_LEN; ++s) {
    int tt = dir ? (TT_LEN - 1 - s) : s;
    int par = s & 1;
    // flush previous step's score (reads wpart[par^1], written before the
    // last barrier; overwritten only after the NEXT barrier)
    if (t == 0 && s > 0) {
      int ttp = dir ? (TT_LEN - s) : (s - 1);
      float sc = 0.0f;
#pragma unroll
      for (int i = 0; i < 8; ++i) sc += wpart[par ^ 1][i];
      scrow[ttp] = sc;
    }
    float acc0a = xgn0, acc1a = xgn1;
    float acc0b = 0.0f, acc1b = 0.0f;
    if (s + 1 < TT_LEN) {
      int t2 = dir ? (TT_LEN - 2 - s) : (s + 1);
      xgn0 = xgbase[(size_t)t2 * G4];
      xgn1 = xgbase[(size_t)t2 * G4 + 512];
    }
    // k<64: LDS weights; h chunks 0..7 (wave-uniform -> broadcast)
#pragma unroll
    for (int c = 0; c < NCH_L2; ++c) {
      uint4 h = hpk4[par][c];
      uint4 w0 = wlds[c * 1024 + t];
      uint4 w1 = wlds[c * 1024 + 512 + t];
      acc0a = dot2acc(w0.x, h.x, acc0a);
      acc0a = dot2acc(w0.y, h.y, acc0a);
      acc0a = dot2acc(w0.z, h.z, acc0a);
      acc0a = dot2acc(w0.w, h.w, acc0a);
      acc1a = dot2acc(w1.x, h.x, acc1a);
      acc1a = dot2acc(w1.y, h.y, acc1a);
      acc1a = dot2acc(w1.z, h.z, acc1a);
      acc1a = dot2acc(w1.w, h.w, acc1a);
    }
    // k=64..255: register weights; h chunks 8..31
#pragma unroll
    for (int g = 0; g < NREG; ++g) {
      uint4 h = hpk4[par][NCH_L2 + g];
      if (g < 12) {
        acc0a = dot2acc(wr0[g].x, h.x, acc0a);
        acc0a = dot2acc(wr0[g].y, h.y, acc0a);
        acc0a = dot2acc(wr0[g].z, h.z, acc0a);
        acc0a = dot2acc(wr0[g].w, h.w, acc0a);
        acc1a = dot2acc(wr1[g].x, h.x, acc1a);
        acc1a = dot2acc(wr1[g].y, h.y, acc1a);
        acc1a = dot2acc(wr1[g].z, h.z, acc1a);
        acc1a = dot2acc(wr1[g].w, h.w, acc1a);
      } else {
        acc0b = dot2acc(wr0[g].x, h.x, acc0b);
        acc0b = dot2acc(wr0[g].y, h.y, acc0b);
        acc0b = dot2acc(wr0[g].z, h.z, acc0b);
        acc0b = dot2acc(wr0[g].w, h.w, acc0b);
        acc1b = dot2acc(wr1[g].x, h.x, acc1b);
        acc1b = dot2acc(wr1[g].y, h.y, acc1b);
        acc1b = dot2acc(wr1[g].z, h.z, acc1b);
        acc1b = dot2acc(wr1[g].w, h.w, acc1b);
      }
    }
    float acc0 = acc0a + acc0b;   // gate (lane&3) of unit U0
    float acc1 = acc1a + acc1b;   // gate (lane&3) of unit 128+U0
    // gather 4 gates of each unit into its collector lane (lane%4==0)
    float f0 = __shfl_down(acc0, 1, 64);
    float g0 = __shfl_down(acc0, 2, 64);
    float o0 = __shfl_down(acc0, 3, 64);
    float f1 = __shfl_down(acc1, 1, 64);
    float g1 = __shfl_down(acc1, 2, 64);
    float o1 = __shfl_down(acc1, 3, 64);
    // activations (all lanes execute; only collector lanes hold real data)
    float ig0 = sigm(acc0), fg0 = sigm(f0), gg0 = tanhf(g0), og0 = sigm(o0);
    cs0 = fg0 * cs0 + ig0 * gg0;
    float h0 = og0 * tanhf(cs0);
    float ig1 = sigm(acc1), fg1 = sigm(f1), gg1 = tanhf(g1), og1 = sigm(o1);
    cs1 = fg1 * cs1 + ig1 * gg1;
    float h1 = og1 * tanhf(cs1);
    // pack unit pairs: lane 8j takes partner h from lane 8j+4
    float hp0 = __shfl_down(h0, 4, 64);
    float hp1 = __shfl_down(h1, 4, 64);
    if ((lane & 7) == 0) {
      ((unsigned int*)hpk4[par ^ 1])[8 * w + (lane >> 3)] = packh(h0, hp0);
      ((unsigned int*)hpk4[par ^ 1])[64 + 8 * w + (lane >> 3)] = packh(h1, hp1);
    }
    // per-wave score partial over collector lanes (strides 4..32)
    float prod = h0 * wo0 + h1 * wo1;
    prod += __shfl_down(prod, 4, 64);
    prod += __shfl_down(prod, 8, 64);
    prod += __shfl_down(prod, 16, 64);
    prod += __shfl_down(prod, 32, 64);
    if (lane == 0) wpart[par][w] = prod;
    __syncthreads();
    (void)tt;
  }
  // flush last step (s=511, par=1)
  if (t == 0) {
    int ttl = dir ? 0 : (TT_LEN - 1);
    float sc = 0.0f;
#pragma unroll
    for (int i = 0; i < 8; ++i) sc += wpart[1][i];
    scrow[ttl] = sc;
  }
}

// ---------------- K4: CRF forward-backward, single wave per batch ----------
__global__ __launch_bounds__(64) void dp2(const float* __restrict__ scores_part,
                                          const float* __restrict__ b_out,
                                          float* __restrict__ ast_g,
                                          float* __restrict__ out) {
  int b = blockIdx.x;
  int l = threadIdx.x;  // 0..63
  const float* spf = scores_part + (size_t)b * TT_LEN;
  const float* spb = scores_part + (size_t)(BB + b) * TT_LEN;
  float bo = b_out[0];
  float* ast = ast_g + (size_t)b * TT_LEN * AST_STRIDE;

  float ur[8];
#pragma unroll
  for (int i = 0; i < 8; ++i)
    ur[i] = (spf[i * 64 + l] + spb[i * 64 + l] + bo) * INV_TEMP;

  int lm1 = (l + 63) & 63;
  int lp1 = (l + 1) & 63;

  float a0[3], a1[3];
  float u00 = __shfl(ur[0], 0, 64);
  a0[0] = (l == 1) ? (u00 + TRANS_T) : NEGF;
  a0[1] = NEGF;
  a0[2] = NEGF;
  a1[0] = (l == 0) ? 0.0f : NEGF;
  a1[1] = NEGF;
  a1[2] = NEGF;
  ast[l] = a0[0];
  ast[64 + l] = a0[1];
  if (l < 27) ast[128 + l] = a0[2];

  // ---- forward t = 1..511 ----
#pragma unroll
  for (int ch = 0; ch < 8; ++ch) {
    float uc = ur[ch];
#pragma unroll 1
    for (int tt = (ch == 0 ? 1 : 0); tt < 64; ++tt) {
      int t = ch * 64 + tt;
      float u0t = __shfl(uc, tt, 64);
      float w0a = __shfl(a0[0], lm1, 64);
      float w1a = __shfl(a0[1], lm1, 64);
      float w2a = __shfl(a0[2], lm1, 64);
      float w0b = __shfl(a1[0], lm1, 64);
      float w1b = __shfl(a1[1], lm1, 64);
      float w2b = __shfl(a1[2], lm1, 64);
      float p0a = (l == 0) ? NEGF : w0a;
      float p1a = (l == 0) ? w0a : w1a;
      float p2a = (l == 0) ? w1a : w2a;
      float p0b = (l == 0) ? NEGF : w0b;
      float p1b = (l == 0) ? w0b : w1b;
      float p2b = (l == 0) ? w1b : w2b;
      float n00 = u0t + la(p0a + TRANS_T, p0b);
      float n01 = u0t + la(p1a + TRANS_T, p1b);
      float n02 = u0t + la(p2a + TRANS_T, p2b);
      float n10 = la(a0[0], a1[0]);
      float n11 = la(a0[1], a1[1]);
      float n12 = la(a0[2], a1[2]);
      a0[0] = n00;
      a0[1] = n01;
      a0[2] = (l < 27) ? n02 : NEGF;
      a1[0] = n10;
      a1[1] = n11;
      a1[2] = (l < 27) ? n12 : NEGF;
      float* astr = ast + (size_t)t * AST_STRIDE;
      astr[l] = a0[0];
      astr[64 + l] = a0[1];
      if (l < 27) astr[128 + l] = a0[2];
    }
  }

  // ---- logZ ----
  float f00 = a0[0] + TRANS_T, f01 = a0[1] + TRANS_T, f02 = a0[2] + TRANS_T;
  float m = fmaxf(fmaxf(fmaxf(f00, f01), fmaxf(f02, a1[0])), fmaxf(a1[1], a1[2]));
#pragma unroll
  for (int off = 32; off > 0; off >>= 1) m = fmaxf(m, __shfl_xor(m, off, 64));
  float es = __expf(f00 - m) + __expf(f01 - m) + __expf(f02 - m) +
             __expf(a1[0] - m) + __expf(a1[1] - m) + __expf(a1[2] - m);
#pragma unroll
  for (int off = 32; off > 0; off >>= 1) es += __shfl_xor(es, off, 64);
  float lz = m + __logf(es);

  // ---- backward init (t = 511) ----
  float b0[3], b1[3];
  b0[0] = TRANS_T;
  b0[1] = TRANS_T;
  b0[2] = (l < 27) ? TRANS_T : NEGF;
  b1[0] = 0.0f;
  b1[1] = 0.0f;
  b1[2] = (l < 27) ? 0.0f : NEGF;
  {
    float ts = __expf(a0[0] + TRANS_T - lz) + __expf(a0[1] + TRANS_T - lz) +
               ((l < 27) ? __expf(a0[2] + TRANS_T - lz) : 0.0f);
#pragma unroll
    for (int off = 32; off > 0; off >>= 1) ts += __shfl_xor(ts, off, 64);
    if (l == 0) out[b * TT_LEN + (TT_LEN - 1)] = ts;
  }

  float nr0 = ast[(size_t)510 * AST_STRIDE + l];
  float nr1 = ast[(size_t)510 * AST_STRIDE + 64 + l];
  float nr2 = (l < 27) ? ast[(size_t)510 * AST_STRIDE + 128 + l] : NEGF;

  // ---- backward t = 511..1 ----
#pragma unroll
  for (int ch = 7; ch >= 0; --ch) {
    float uc = ur[ch];
#pragma unroll 1
    for (int tt = 63; tt >= (ch == 0 ? 1 : 0); --tt) {
      int t = ch * 64 + tt;
      float u0t = __shfl(uc, tt, 64);
      float c0 = nr0, c1 = nr1, c2 = nr2;
      if (t >= 2) {
        const float* astr = ast + (size_t)(t - 2) * AST_STRIDE;
        nr0 = astr[l];
        nr1 = astr[64 + l];
        nr2 = (l < 27) ? astr[128 + l] : NEGF;
      }
      float w0 = __shfl(b0[0], lp1, 64);
      float w1 = __shfl(b0[1], lp1, 64);
      float w2 = __shfl(b0[2], lp1, 64);
      float x2 = (l == 63) ? NEGF : w2;
      float x1 = (l == 63) ? w2 : w1;
      float x0 = (l == 63) ? w1 : w0;
      float nb00 = la(u0t + TRANS_T + x0, b1[0]);
      float nb01 = la(u0t + TRANS_T + x1, b1[1]);
      float nb02 = la(u0t + TRANS_T + x2, b1[2]);
      float nb10 = la(u0t + x0, b1[0]);
      float nb11 = la(u0t + x1, b1[1]);
      float nb12 = la(u0t + x2, b1[2]);
      float tm = __expf(c0 + nb00 - lz) + __expf(c1 + nb01 - lz) +
                 ((l < 27) ? __expf(c2 + nb02 - lz) : 0.0f);
#pragma unroll
      for (int off = 32; off > 0; off >>= 1) tm += __shfl_xor(tm, off, 64);
      if (l == 0) out[b * TT_LEN + (t - 1)] = tm;
      b0[0] = nb00;
      b0[1] = nb01;
      b0[2] = (l < 27) ? nb02 : NEGF;
      b1[0] = nb10;
      b1[1] = nb11;
      b1[2] = (l < 27) ? nb12 : NEGF;
    }
  }
}

// ---------------------------------------------------------------------------
extern "C" void kernel_launch(void* const* d_in, const int* in_sizes, int n_in,
                              void* d_out, int out_size, void* d_ws, size_t ws_size,
                              hipStream_t stream) {
  const int* x = (const int*)d_in[0];
  const float* embed = (const float*)d_in[3];
  const float* wi_f = (const float*)d_in[4];
  const float* wh_f = (const float*)d_in[5];
  const float* bf = (const float*)d_in[6];
  const float* wi_b = (const float*)d_in[7];
  const float* wh_b = (const float*)d_in[8];
  const float* bbias = (const float*)d_in[9];
  const float* w_out = (const float*)d_in[10];
  const float* b_out = (const float*)d_in[11];

  float* ws = (float*)d_ws;
  float* b_p = ws;                                      // 2*1024 f32
  unsigned int* wlds_h = (unsigned int*)(b_p + 2 * G4); // 2*8*4096 dwords
  unsigned int* wstr_h = wlds_h + 2 * NCH_L2 * 4096;    // 2*24*4096 dwords
  _Float16* wi_t = (_Float16*)(wstr_h + 2 * NREG * 4096);  // 2*1024*320 f16
  _Float16* emb_h = wi_t + (size_t)2 * G4 * KPAD;       // 16384*320 f16
  float* xg = (float*)(emb_h + (size_t)BB * TT_LEN * KPAD);  // 2*16384*1024 f32
  float* scores_part = xg + (size_t)2 * BB * TT_LEN * G4;    // 2*16384
  float* u0_unused = scores_part + 2 * BB * TT_LEN;     // 16384 (layout keep)
  float* ast_g = u0_unused + BB * TT_LEN;               // 32*512*160 f32
  float* outp = (float*)d_out;

  prep_weights<<<256, 256, 0, stream>>>(wi_f, wi_b, wh_f, wh_b, bf, bbias,
                                        wi_t, b_p, wlds_h, wstr_h);
  gather_emb<<<BB * TT_LEN, 256, 0, stream>>>(x, embed, emb_h);
  dim3 g1(G4 / 64, (BB * TT_LEN) / 64, 2);
  xg_mfma<<<g1, 256, 0, stream>>>(emb_h, wi_t, b_p, xg);
  lstm_v5<<<64, 512, 0, stream>>>(xg, wlds_h, (const uint4*)wstr_h, w_out,
                                  scores_part);
  dp2<<<BB, 64, 0, stream>>>(scores_part, b_out, ast_g, outp);
}

// Round 12
// 1892.924 us; speedup vs baseline: 1.4347x; 1.0575x over previous
//
#include <hip/hip_runtime.h>
#include <math.h>

// Problem constants (reference: B,T,V,E,H = 32,512,32000,300,256)
#define BB 32
#define TT_LEN 512
#define EE 300
#define KPAD 320         // EE padded to multiple of 32 for MFMA K
#define HH 256
#define G4 1024          // 4*H
#define CMAX 155         // int(round(0.3*512))+1
#define TRANS_T 10.0f    // TRANSITION/TEMP
#define NEGF -1.0e9f
#define INV_TEMP 100.0f  // 1/TEMP
#define AST_STRIDE 159   // >155 needed; 159 keeps total ws under round-5 cap

// lstm weight split (round-8 proven, no spill): LDS part = 8 uint4-chunks
// (k<64, 128 KB), register part = 24 uint4-chunks (k=64..255, 192 dwords).
#define NCH_L2 8
#define NREG 24

typedef _Float16 half2v __attribute__((ext_vector_type(2)));
typedef _Float16 half8 __attribute__((ext_vector_type(8)));
typedef float f32x4 __attribute__((ext_vector_type(4)));

__device__ __forceinline__ float la(float x, float y) {
  float m = fmaxf(x, y);
  float d = fminf(x, y) - m;
  return m + __logf(1.0f + __expf(d));
}

__device__ __forceinline__ float sigm(float x) {
  return 1.0f / (1.0f + __expf(-x));
}

__device__ __forceinline__ float dot2acc(unsigned int wd, unsigned int hd, float acc) {
#if __has_builtin(__builtin_amdgcn_fdot2)
  return __builtin_amdgcn_fdot2(__builtin_bit_cast(half2v, wd),
                                __builtin_bit_cast(half2v, hd), acc, false);
#else
  half2v a = __builtin_bit_cast(half2v, wd);
  half2v b = __builtin_bit_cast(half2v, hd);
  return acc + (float)a.x * (float)b.x + (float)a.y * (float)b.y;
#endif
}

__device__ __forceinline__ unsigned int packh(float a, float b) {
  half2v hp;
  hp.x = (_Float16)a;
  hp.y = (_Float16)b;
  return __builtin_bit_cast(unsigned int, hp);
}

// ---------------- K0: weight prep ------------------------------------------
// wi_frag: B operand pre-swizzled to MFMA fragment order. uint4 index
//   ((dir*64 + nblk)*10 + kk)*64 + lane, lane = l15 + 16*quad holds col
//   n = nblk*16+l15, k = kk*32+quad*8 .. +8 (f16 pairs per dword). Every
//   xg_mfma B-load is then one fully-coalesced b128.
// wh packed f16 dwords (round-8 layout, unchanged):
//   LDS part  wlds_h: idx ((dir*NCH_L2 + c)*1024 + j)*4 + d, k0 = 8c+2d
//   reg part  wstr_h: idx ((dir*NREG + g)*1024 + j)*4 + d, k0 = 64+8g+2d
__global__ void prep_weights(const float* wi_f, const float* wi_b,
                             const float* wh_f, const float* wh_b,
                             const float* b_f, const float* b_b,
                             unsigned int* wi_frag, float* b_p,
                             unsigned int* wlds_h, unsigned int* wstr_h) {
  int idx = blockIdx.x * blockDim.x + threadIdx.x;
  int stride = gridDim.x * blockDim.x;
  // wi fragment pack: 2*64*10*64 uint4 = 327680 dwords
  for (int i = idx; i < 2 * 64 * 10 * 64 * 4; i += stride) {
    int u4 = i >> 2, d = i & 3;
    int lane = u4 & 63;
    int kk = (u4 >> 6) % 10;
    int nb = (u4 / 640) & 63;
    int dir = u4 / (640 * 64);
    int l15 = lane & 15, quad = lane >> 4;
    int n = nb * 16 + l15;         // permuted gate col j' = u*4+g
    int g = n & 3, u = n >> 2;
    int k0 = kk * 32 + quad * 8 + 2 * d;
    const float* src = dir ? wi_b : wi_f;
    float v0 = (k0 < EE) ? src[(size_t)k0 * G4 + g * HH + u] : 0.0f;
    float v1 = (k0 + 1 < EE) ? src[(size_t)(k0 + 1) * G4 + g * HH + u] : 0.0f;
    wi_frag[i] = packh(v0, v1);
  }
  for (int i = idx; i < 2 * NCH_L2 * 4096; i += stride) {
    int dir = i / (NCH_L2 * 4096);
    int r = i % (NCH_L2 * 4096);
    int c = r / 4096;
    int r2 = r % 4096;
    int j = r2 >> 2, d = r2 & 3;
    int g = j & 3, u = j >> 2;
    int k0 = 8 * c + 2 * d;
    const float* src = dir ? wh_b : wh_f;
    wlds_h[i] = packh(src[k0 * G4 + g * HH + u], src[(k0 + 1) * G4 + g * HH + u]);
  }
  for (int i = idx; i < 2 * NREG * 4096; i += stride) {
    int dir = i / (NREG * 4096);
    int r = i % (NREG * 4096);
    int gch = r / 4096;
    int r2 = r % 4096;
    int j = r2 >> 2, d = r2 & 3;
    int g = j & 3, u = j >> 2;
    int k0 = 64 + 8 * gch + 2 * d;
    const float* src = dir ? wh_b : wh_f;
    wstr_h[i] = packh(src[k0 * G4 + g * HH + u], src[(k0 + 1) * G4 + g * HH + u]);
  }
  for (int i = idx; i < 2 * G4; i += stride) {
    int dir = i / G4;
    int j = i % G4;
    int g = j & 3, u = j >> 2;
    const float* src = dir ? b_b : b_f;
    b_p[i] = src[g * HH + u];
  }
}

// ---------------- K_emb: gather -> A-fragment layout -----------------------
// emb_frag uint4 idx (mblk*10 + kk)*64 + lane, lane = l15+16*quad holds row
// m = mblk*16+l15, k = kk*32+quad*8 .. +8 as f16 (zeros k>=300). One block
// per mblk (16 rows).
__global__ void gather_emb(const int* x, const float* embed, uint4* emb_frag) {
  int mblk = blockIdx.x;
  int t = threadIdx.x;
  __shared__ int xs[16];
  if (t < 16) xs[t] = x[mblk * 16 + t];
  __syncthreads();
  for (int slot = t; slot < 640; slot += 256) {
    int kk = slot >> 6;
    int lane = slot & 63;
    int l15 = lane & 15, quad = lane >> 4;
    int row = xs[l15];
    int kbase = kk * 32 + quad * 8;
    const float* src = embed + (size_t)row * EE;
    float v[8];
#pragma unroll
    for (int e = 0; e < 8; ++e) v[e] = (kbase + e < EE) ? src[kbase + e] : 0.0f;
    uint4 o;
    o.x = packh(v[0], v[1]);
    o.y = packh(v[2], v[3]);
    o.z = packh(v[4], v[5]);
    o.w = packh(v[6], v[7]);
    emb_frag[(size_t)(mblk * 10 + kk) * 64 + lane] = o;
  }
}

// ---------------- K1: xg = emb @ wi^T + b  (f16 MFMA, coalesced frags) -----
// Every A/B load is one coalesced b128 (fragment-order layouts above).
// D layout unchanged: col=l15, row=quad*4+r (proven since round 5).
__global__ __launch_bounds__(256) void xg_mfma(
    const uint4* __restrict__ emb_frag, const uint4* __restrict__ wi_frag,
    const float* __restrict__ b_p, float* __restrict__ xg) {
  int dir = blockIdx.z;
  int w = threadIdx.x >> 6;
  int lane = threadIdx.x & 63;
  int l15 = lane & 15, quad = lane >> 4;
  int mblk = blockIdx.y * 4 + w;

  const uint4* abase = emb_frag + (size_t)mblk * 10 * 64 + lane;
  f32x4 acc[4];
#pragma unroll
  for (int nt = 0; nt < 4; ++nt) acc[nt] = (f32x4){0.f, 0.f, 0.f, 0.f};

#pragma unroll
  for (int kk = 0; kk < 10; ++kk) {
    half8 a = __builtin_bit_cast(half8, abase[kk * 64]);
#pragma unroll
    for (int nt = 0; nt < 4; ++nt) {
      int nb = blockIdx.x * 4 + nt;
      half8 b = __builtin_bit_cast(
          half8, wi_frag[((size_t)(dir * 64 + nb) * 10 + kk) * 64 + lane]);
      acc[nt] = __builtin_amdgcn_mfma_f32_16x16x32_f16(a, b, acc[nt], 0, 0, 0);
    }
  }
#pragma unroll
  for (int nt = 0; nt < 4; ++nt) {
    int n = (blockIdx.x * 4 + nt) * 16 + l15;
    float bias = b_p[dir * G4 + n];
#pragma unroll
    for (int r = 0; r < 4; ++r) {
      int m = mblk * 16 + quad * 4 + r;
      xg[((size_t)dir * (BB * TT_LEN) + m) * G4 + n] = acc[nt][r] + bias;
    }
  }
}

// ---------------- K2: LSTM chunked (round-8 proven body + state I/O) -------
// 64 blocks (dir,b), 512 threads. Runs steps [s0i, s1i); h (packed f16) and
// c (f32) state through global between chunks. 4 chunks of 128 steps ->
// each dispatch ~280 us, making any hidden "rest" kernel >290 us visible
// in the top-5 profile (the measurement goal of this round).
__global__ __launch_bounds__(512, 2) void lstm_ck(
    const float* __restrict__ xg, const unsigned int* __restrict__ wlds_h,
    const uint4* __restrict__ wstr, const float* __restrict__ w_out,
    float* __restrict__ scores_part, float* __restrict__ hst,
    float* __restrict__ cst, int s0i, int s1i) {
  int bid = blockIdx.x;            // 64 blocks: dir*32 + b
  int dir = bid >> 5, b = bid & 31;
  int t = threadIdx.x;             // 0..511
  int lane = t & 63, wid = t >> 6;

  __shared__ uint4 wlds[NCH_L2 * 1024];  // 128 KB
  __shared__ uint4 hpk4[32];             // 256 h as 128 packed-f16 dwords
  __shared__ float gates[1024];
  __shared__ float wpart[2][4];

  const uint4* wsrcl = (const uint4*)wlds_h + (size_t)dir * (NCH_L2 * 1024);
  for (int i = t; i < NCH_L2 * 1024; i += 512) wlds[i] = wsrcl[i];
  const uint4* wsb = wstr + (size_t)dir * (NREG * 1024);
  uint4 wr0[NREG], wr1[NREG];
#pragma unroll
  for (int g = 0; g < NREG; ++g) {
    wr0[g] = wsb[g * 1024 + t];
    wr1[g] = wsb[g * 1024 + t + 512];
  }
  if (t < 32)
    hpk4[t] = (s0i == 0) ? uint4{0, 0, 0, 0} : ((const uint4*)hst)[bid * 32 + t];
  float cstate = 0.0f;
  if (s0i > 0 && t < HH) cstate = cst[bid * HH + t];
  __syncthreads();

  const float* xgbase =
      xg + (size_t)(dir * (BB * TT_LEN) + b * TT_LEN) * G4 + t;
  float wo = (t < HH) ? w_out[dir * HH + t] : 0.0f;

  int t0 = dir ? (TT_LEN - 1 - s0i) : s0i;
  float xgn0 = xgbase[(size_t)t0 * G4];
  float xgn1 = xgbase[(size_t)t0 * G4 + 512];

#pragma unroll 1
  for (int s = s0i; s < s1i; ++s) {
    int tt = dir ? (TT_LEN - 1 - s) : s;
    float acc0a = xgn0, acc1a = xgn1;
    float acc0b = 0.0f, acc1b = 0.0f;
    if (s + 1 < TT_LEN) {
      int t2 = dir ? (TT_LEN - 2 - s) : (s + 1);
      xgn0 = xgbase[(size_t)t2 * G4];
      xgn1 = xgbase[(size_t)t2 * G4 + 512];
    }
#pragma unroll
    for (int c = 0; c < NCH_L2; ++c) {
      uint4 h = hpk4[c];
      uint4 w0 = wlds[c * 1024 + t];
      uint4 w1 = wlds[c * 1024 + 512 + t];
      acc0a = dot2acc(w0.x, h.x, acc0a);
      acc0a = dot2acc(w0.y, h.y, acc0a);
      acc0a = dot2acc(w0.z, h.z, acc0a);
      acc0a = dot2acc(w0.w, h.w, acc0a);
      acc1a = dot2acc(w1.x, h.x, acc1a);
      acc1a = dot2acc(w1.y, h.y, acc1a);
      acc1a = dot2acc(w1.z, h.z, acc1a);
      acc1a = dot2acc(w1.w, h.w, acc1a);
    }
#pragma unroll
    for (int g = 0; g < NREG; ++g) {
      uint4 h = hpk4[NCH_L2 + g];
      if (g < 12) {
        acc0a = dot2acc(wr0[g].x, h.x, acc0a);
        acc0a = dot2acc(wr0[g].y, h.y, acc0a);
        acc0a = dot2acc(wr0[g].z, h.z, acc0a);
        acc0a = dot2acc(wr0[g].w, h.w, acc0a);
        acc1a = dot2acc(wr1[g].x, h.x, acc1a);
        acc1a = dot2acc(wr1[g].y, h.y, acc1a);
        acc1a = dot2acc(wr1[g].z, h.z, acc1a);
        acc1a = dot2acc(wr1[g].w, h.w, acc1a);
      } else {
        acc0b = dot2acc(wr0[g].x, h.x, acc0b);
        acc0b = dot2acc(wr0[g].y, h.y, acc0b);
        acc0b = dot2acc(wr0[g].z, h.z, acc0b);
        acc0b = dot2acc(wr0[g].w, h.w, acc0b);
        acc1b = dot2acc(wr1[g].x, h.x, acc1b);
        acc1b = dot2acc(wr1[g].y, h.y, acc1b);
        acc1b = dot2acc(wr1[g].z, h.z, acc1b);
        acc1b = dot2acc(wr1[g].w, h.w, acc1b);
      }
    }
    gates[t] = acc0a + acc0b;
    gates[512 + t] = acc1a + acc1b;
    __syncthreads();

    if (t < HH) {
      float4 g4 = ((const float4*)gates)[t];
      float ig = sigm(g4.x);
      float fg = sigm(g4.y);
      float gg = tanhf(g4.z);
      float og = sigm(g4.w);
      cstate = fg * cstate + ig * gg;
      float h = og * tanhf(cstate);
      float prod = h * wo;
#pragma unroll
      for (int off = 32; off > 0; off >>= 1) prod += __shfl_down(prod, off, 64);
      if (lane == 0) wpart[s & 1][wid] = prod;
      float hn = __shfl_down(h, 1, 64);
      if (!(t & 1)) ((unsigned int*)hpk4)[t >> 1] = packh(h, hn);
    }
    __syncthreads();
    if (t == 0) {
      scores_part[(size_t)(dir * BB + b) * TT_LEN + tt] =
          wpart[s & 1][0] + wpart[s & 1][1] + wpart[s & 1][2] + wpart[s & 1][3];
    }
  }
  // save state for next chunk (hpk4 consistent after final barrier)
  if (t < 32) ((uint4*)hst)[bid * 32 + t] = hpk4[t];
  if (t < HH) cst[bid * HH + t] = cstate;
}

// ---------------- K4: CRF forward-backward, single wave per batch ----------
__global__ __launch_bounds__(64) void dp2(const float* __restrict__ scores_part,
                                          const float* __restrict__ b_out,
                                          float* __restrict__ ast_g,
                                          float* __restrict__ out) {
  int b = blockIdx.x;
  int l = threadIdx.x;  // 0..63
  const float* spf = scores_part + (size_t)b * TT_LEN;
  const float* spb = scores_part + (size_t)(BB + b) * TT_LEN;
  float bo = b_out[0];
  float* ast = ast_g + (size_t)b * TT_LEN * AST_STRIDE;

  float ur[8];
#pragma unroll
  for (int i = 0; i < 8; ++i)
    ur[i] = (spf[i * 64 + l] + spb[i * 64 + l] + bo) * INV_TEMP;

  int lm1 = (l + 63) & 63;
  int lp1 = (l + 1) & 63;

  float a0[3], a1[3];
  float u00 = __shfl(ur[0], 0, 64);
  a0[0] = (l == 1) ? (u00 + TRANS_T) : NEGF;
  a0[1] = NEGF;
  a0[2] = NEGF;
  a1[0] = (l == 0) ? 0.0f : NEGF;
  a1[1] = NEGF;
  a1[2] = NEGF;
  ast[l] = a0[0];
  ast[64 + l] = a0[1];
  if (l < 27) ast[128 + l] = a0[2];

  // ---- forward t = 1..511 ----
#pragma unroll
  for (int ch = 0; ch < 8; ++ch) {
    float uc = ur[ch];
#pragma unroll 1
    for (int tt = (ch == 0 ? 1 : 0); tt < 64; ++tt) {
      int t = ch * 64 + tt;
      float u0t = __shfl(uc, tt, 64);
      float w0a = __shfl(a0[0], lm1, 64);
      float w1a = __shfl(a0[1], lm1, 64);
      float w2a = __shfl(a0[2], lm1, 64);
      float w0b = __shfl(a1[0], lm1, 64);
      float w1b = __shfl(a1[1], lm1, 64);
      float w2b = __shfl(a1[2], lm1, 64);
      float p0a = (l == 0) ? NEGF : w0a;
      float p1a = (l == 0) ? w0a : w1a;
      float p2a = (l == 0) ? w1a : w2a;
      float p0b = (l == 0) ? NEGF : w0b;
      float p1b = (l == 0) ? w0b : w1b;
      float p2b = (l == 0) ? w1b : w2b;
      float n00 = u0t + la(p0a + TRANS_T, p0b);
      float n01 = u0t + la(p1a + TRANS_T, p1b);
      float n02 = u0t + la(p2a + TRANS_T, p2b);
      float n10 = la(a0[0], a1[0]);
      float n11 = la(a0[1], a1[1]);
      float n12 = la(a0[2], a1[2]);
      a0[0] = n00;
      a0[1] = n01;
      a0[2] = (l < 27) ? n02 : NEGF;
      a1[0] = n10;
      a1[1] = n11;
      a1[2] = (l < 27) ? n12 : NEGF;
      float* astr = ast + (size_t)t * AST_STRIDE;
      astr[l] = a0[0];
      astr[64 + l] = a0[1];
      if (l < 27) astr[128 + l] = a0[2];
    }
  }

  // ---- logZ ----
  float f00 = a0[0] + TRANS_T, f01 = a0[1] + TRANS_T, f02 = a0[2] + TRANS_T;
  float m = fmaxf(fmaxf(fmaxf(f00, f01), fmaxf(f02, a1[0])), fmaxf(a1[1], a1[2]));
#pragma unroll
  for (int off = 32; off > 0; off >>= 1) m = fmaxf(m, __shfl_xor(m, off, 64));
  float es = __expf(f00 - m) + __expf(f01 - m) + __expf(f02 - m) +
             __expf(a1[0] - m) + __expf(a1[1] - m) + __expf(a1[2] - m);
#pragma unroll
  for (int off = 32; off > 0; off >>= 1) es += __shfl_xor(es, off, 64);
  float lz = m + __logf(es);

  // ---- backward init (t = 511) ----
  float b0[3], b1[3];
  b0[0] = TRANS_T;
  b0[1] = TRANS_T;
  b0[2] = (l < 27) ? TRANS_T : NEGF;
  b1[0] = 0.0f;
  b1[1] = 0.0f;
  b1[2] = (l < 27) ? 0.0f : NEGF;
  {
    float ts = __expf(a0[0] + TRANS_T - lz) + __expf(a0[1] + TRANS_T - lz) +
               ((l < 27) ? __expf(a0[2] + TRANS_T - lz) : 0.0f);
#pragma unroll
    for (int off = 32; off > 0; off >>= 1) ts += __shfl_xor(ts, off, 64);
    if (l == 0) out[b * TT_LEN + (TT_LEN - 1)] = ts;
  }

  float nr0 = ast[(size_t)510 * AST_STRIDE + l];
  float nr1 = ast[(size_t)510 * AST_STRIDE + 64 + l];
  float nr2 = (l < 27) ? ast[(size_t)510 * AST_STRIDE + 128 + l] : NEGF;

  // ---- backward t = 511..1 ----
#pragma unroll
  for (int ch = 7; ch >= 0; --ch) {
    float uc = ur[ch];
#pragma unroll 1
    for (int tt = 63; tt >= (ch == 0 ? 1 : 0); --tt) {
      int t = ch * 64 + tt;
      float u0t = __shfl(uc, tt, 64);
      float c0 = nr0, c1 = nr1, c2 = nr2;
      if (t >= 2) {
        const float* astr = ast + (size_t)(t - 2) * AST_STRIDE;
        nr0 = astr[l];
        nr1 = astr[64 + l];
        nr2 = (l < 27) ? astr[128 + l] : NEGF;
      }
      float w0 = __shfl(b0[0], lp1, 64);
      float w1 = __shfl(b0[1], lp1, 64);
      float w2 = __shfl(b0[2], lp1, 64);
      float x2 = (l == 63) ? NEGF : w2;
      float x1 = (l == 63) ? w2 : w1;
      float x0 = (l == 63) ? w1 : w0;
      float nb00 = la(u0t + TRANS_T + x0, b1[0]);
      float nb01 = la(u0t + TRANS_T + x1, b1[1]);
      float nb02 = la(u0t + TRANS_T + x2, b1[2]);
      float nb10 = la(u0t + x0, b1[0]);
      float nb11 = la(u0t + x1, b1[1]);
      float nb12 = la(u0t + x2, b1[2]);
      float tm = __expf(c0 + nb00 - lz) + __expf(c1 + nb01 - lz) +
                 ((l < 27) ? __expf(c2 + nb02 - lz) : 0.0f);
#pragma unroll
      for (int off = 32; off > 0; off >>= 1) tm += __shfl_xor(tm, off, 64);
      if (l == 0) out[b * TT_LEN + (t - 1)] = tm;
      b0[0] = nb00;
      b0[1] = nb01;
      b0[2] = (l < 27) ? nb02 : NEGF;
      b1[0] = nb10;
      b1[1] = nb11;
      b1[2] = (l < 27) ? nb12 : NEGF;
    }
  }
}

// ---------------------------------------------------------------------------
extern "C" void kernel_launch(void* const* d_in, const int* in_sizes, int n_in,
                              void* d_out, int out_size, void* d_ws, size_t ws_size,
                              hipStream_t stream) {
  const int* x = (const int*)d_in[0];
  const float* embed = (const float*)d_in[3];
  const float* wi_f = (const float*)d_in[4];
  const float* wh_f = (const float*)d_in[5];
  const float* bf = (const float*)d_in[6];
  const float* wi_b = (const float*)d_in[7];
  const float* wh_b = (const float*)d_in[8];
  const float* bbias = (const float*)d_in[9];
  const float* w_out = (const float*)d_in[10];
  const float* b_out = (const float*)d_in[11];

  float* ws = (float*)d_ws;
  float* b_p = ws;                                      // 2048 f32
  unsigned int* wlds_h = (unsigned int*)(b_p + 2 * G4); // 65536 dw
  unsigned int* wstr_h = wlds_h + 2 * NCH_L2 * 4096;    // 196608 dw
  unsigned int* wi_frag = wstr_h + 2 * NREG * 4096;     // 327680 dw
  uint4* emb_frag = (uint4*)(wi_frag + 2 * 64 * 10 * 64 * 4);  // 655360 uint4
  float* xg = (float*)(emb_frag + (size_t)1024 * 10 * 64);     // 33554432 f32
  float* scores_part = xg + (size_t)2 * BB * TT_LEN * G4;      // 32768 f32
  float* hst = scores_part + 2 * BB * TT_LEN;           // 8192 dw (64*32 uint4)
  float* cst = hst + 64 * 32 * 4;                       // 16384 f32
  float* ast_g = cst + 64 * HH;                         // 32*512*159 f32
  float* outp = (float*)d_out;

  prep_weights<<<256, 256, 0, stream>>>(wi_f, wi_b, wh_f, wh_b, bf, bbias,
                                        wi_frag, b_p, wlds_h, wstr_h);
  gather_emb<<<(BB * TT_LEN) / 16, 256, 0, stream>>>(x, embed, emb_frag);
  dim3 g1(16, 256, 2);
  xg_mfma<<<g1, 256, 0, stream>>>(emb_frag, (const uint4*)wi_frag, b_p, xg);
  for (int c = 0; c < 4; ++c) {
    lstm_ck<<<64, 512, 0, stream>>>(xg, wlds_h, (const uint4*)wstr_h, w_out,
                                    scores_part, hst, cst, c * 128,
                                    (c + 1) * 128);
  }
  dp2<<<BB, 64, 0, stream>>>(scores_part, b_out, ast_g, outp);
}

// Round 13
// 1554.317 us; speedup vs baseline: 1.7472x; 1.2178x over previous
//
#include <hip/hip_runtime.h>
#include <math.h>

// Problem constants (reference: B,T,V,E,H = 32,512,32000,300,256)
#define BB 32
#define TT_LEN 512
#define EE 300
#define HH 256
#define G4 1024          // 4*H
#define CMAX 155         // int(round(0.3*512))+1
#define TRANS_T 10.0f    // TRANSITION/TEMP
#define NEGF -1.0e9f
#define INV_TEMP 100.0f  // 1/TEMP
#define AST_STRIDE 159   // slot-2 accesses predicated l<27 (max off 154)

// lstm weight split (round-8 proven, no spill): LDS part = 8 uint4-chunks
// (k<64, 128 KB), register part = 24 uint4-chunks (k=64..255, 192 dwords).
#define NCH_L2 8
#define NREG 24

typedef _Float16 half2v __attribute__((ext_vector_type(2)));
typedef _Float16 half8 __attribute__((ext_vector_type(8)));
typedef float f32x4 __attribute__((ext_vector_type(4)));

__device__ __forceinline__ float la(float x, float y) {
  float m = fmaxf(x, y);
  float d = fminf(x, y) - m;
  return m + __logf(1.0f + __expf(d));
}

__device__ __forceinline__ float sigm(float x) {
  return 1.0f / (1.0f + __expf(-x));
}

__device__ __forceinline__ float dot2acc(unsigned int wd, unsigned int hd, float acc) {
#if __has_builtin(__builtin_amdgcn_fdot2)
  return __builtin_amdgcn_fdot2(__builtin_bit_cast(half2v, wd),
                                __builtin_bit_cast(half2v, hd), acc, false);
#else
  half2v a = __builtin_bit_cast(half2v, wd);
  half2v b = __builtin_bit_cast(half2v, hd);
  return acc + (float)a.x * (float)b.x + (float)a.y * (float)b.y;
#endif
}

__device__ __forceinline__ unsigned int packh(float a, float b) {
  half2v hp;
  hp.x = (_Float16)a;
  hp.y = (_Float16)b;
  return __builtin_bit_cast(unsigned int, hp);
}

// ---------------- K0: weight prep (round-12 version, unchanged) ------------
__global__ void prep_weights(const float* wi_f, const float* wi_b,
                             const float* wh_f, const float* wh_b,
                             const float* b_f, const float* b_b,
                             unsigned int* wi_frag, float* b_p,
                             unsigned int* wlds_h, unsigned int* wstr_h) {
  int idx = blockIdx.x * blockDim.x + threadIdx.x;
  int stride = gridDim.x * blockDim.x;
  for (int i = idx; i < 2 * 64 * 10 * 64 * 4; i += stride) {
    int u4 = i >> 2, d = i & 3;
    int lane = u4 & 63;
    int kk = (u4 >> 6) % 10;
    int nb = (u4 / 640) & 63;
    int dir = u4 / (640 * 64);
    int l15 = lane & 15, quad = lane >> 4;
    int n = nb * 16 + l15;
    int g = n & 3, u = n >> 2;
    int k0 = kk * 32 + quad * 8 + 2 * d;
    const float* src = dir ? wi_b : wi_f;
    float v0 = (k0 < EE) ? src[(size_t)k0 * G4 + g * HH + u] : 0.0f;
    float v1 = (k0 + 1 < EE) ? src[(size_t)(k0 + 1) * G4 + g * HH + u] : 0.0f;
    wi_frag[i] = packh(v0, v1);
  }
  for (int i = idx; i < 2 * NCH_L2 * 4096; i += stride) {
    int dir = i / (NCH_L2 * 4096);
    int r = i % (NCH_L2 * 4096);
    int c = r / 4096;
    int r2 = r % 4096;
    int j = r2 >> 2, d = r2 & 3;
    int g = j & 3, u = j >> 2;
    int k0 = 8 * c + 2 * d;
    const float* src = dir ? wh_b : wh_f;
    wlds_h[i] = packh(src[k0 * G4 + g * HH + u], src[(k0 + 1) * G4 + g * HH + u]);
  }
  for (int i = idx; i < 2 * NREG * 4096; i += stride) {
    int dir = i / (NREG * 4096);
    int r = i % (NREG * 4096);
    int gch = r / 4096;
    int r2 = r % 4096;
    int j = r2 >> 2, d = r2 & 3;
    int g = j & 3, u = j >> 2;
    int k0 = 64 + 8 * gch + 2 * d;
    const float* src = dir ? wh_b : wh_f;
    wstr_h[i] = packh(src[k0 * G4 + g * HH + u], src[(k0 + 1) * G4 + g * HH + u]);
  }
  for (int i = idx; i < 2 * G4; i += stride) {
    int dir = i / G4;
    int j = i % G4;
    int g = j & 3, u = j >> 2;
    const float* src = dir ? b_b : b_f;
    b_p[i] = src[g * HH + u];
  }
}

// ---------------- K_emb: gather -> A-fragment layout (unchanged) -----------
__global__ void gather_emb(const int* x, const float* embed, uint4* emb_frag) {
  int mblk = blockIdx.x;
  int t = threadIdx.x;
  __shared__ int xs[16];
  if (t < 16) xs[t] = x[mblk * 16 + t];
  __syncthreads();
  for (int slot = t; slot < 640; slot += 256) {
    int kk = slot >> 6;
    int lane = slot & 63;
    int l15 = lane & 15, quad = lane >> 4;
    int row = xs[l15];
    int kbase = kk * 32 + quad * 8;
    const float* src = embed + (size_t)row * EE;
    float v[8];
#pragma unroll
    for (int e = 0; e < 8; ++e) v[e] = (kbase + e < EE) ? src[kbase + e] : 0.0f;
    uint4 o;
    o.x = packh(v[0], v[1]);
    o.y = packh(v[2], v[3]);
    o.z = packh(v[4], v[5]);
    o.w = packh(v[6], v[7]);
    emb_frag[(size_t)(mblk * 10 + kk) * 64 + lane] = o;
  }
}

// ---------------- K1: xg = emb @ wi^T + b  (f16 MFMA, coalesced frags) -----
__global__ __launch_bounds__(256) void xg_mfma(
    const uint4* __restrict__ emb_frag, const uint4* __restrict__ wi_frag,
    const float* __restrict__ b_p, float* __restrict__ xg) {
  int dir = blockIdx.z;
  int w = threadIdx.x >> 6;
  int lane = threadIdx.x & 63;
  int l15 = lane & 15, quad = lane >> 4;
  int mblk = blockIdx.y * 4 + w;

  const uint4* abase = emb_frag + (size_t)mblk * 10 * 64 + lane;
  f32x4 acc[4];
#pragma unroll
  for (int nt = 0; nt < 4; ++nt) acc[nt] = (f32x4){0.f, 0.f, 0.f, 0.f};

#pragma unroll
  for (int kk = 0; kk < 10; ++kk) {
    half8 a = __builtin_bit_cast(half8, abase[kk * 64]);
#pragma unroll
    for (int nt = 0; nt < 4; ++nt) {
      int nb = blockIdx.x * 4 + nt;
      half8 b = __builtin_bit_cast(
          half8, wi_frag[((size_t)(dir * 64 + nb) * 10 + kk) * 64 + lane]);
      acc[nt] = __builtin_amdgcn_mfma_f32_16x16x32_f16(a, b, acc[nt], 0, 0, 0);
    }
  }
#pragma unroll
  for (int nt = 0; nt < 4; ++nt) {
    int n = (blockIdx.x * 4 + nt) * 16 + l15;
    float bias = b_p[dir * G4 + n];
#pragma unroll
    for (int r = 0; r < 4; ++r) {
      int m = mblk * 16 + quad * 4 + r;
      xg[((size_t)dir * (BB * TT_LEN) + m) * G4 + n] = acc[nt][r] + bias;
    }
  }
}

// ---------------- K2: LSTM (round-8 proven body, single launch) ------------
__global__ __launch_bounds__(512, 2) void lstm_ck(
    const float* __restrict__ xg, const unsigned int* __restrict__ wlds_h,
    const uint4* __restrict__ wstr, const float* __restrict__ w_out,
    float* __restrict__ scores_part) {
  int bid = blockIdx.x;            // 64 blocks: dir*32 + b
  int dir = bid >> 5, b = bid & 31;
  int t = threadIdx.x;             // 0..511
  int lane = t & 63, wid = t >> 6;

  __shared__ uint4 wlds[NCH_L2 * 1024];  // 128 KB
  __shared__ uint4 hpk4[32];             // 256 h as 128 packed-f16 dwords
  __shared__ float gates[1024];
  __shared__ float wpart[2][4];

  const uint4* wsrcl = (const uint4*)wlds_h + (size_t)dir * (NCH_L2 * 1024);
  for (int i = t; i < NCH_L2 * 1024; i += 512) wlds[i] = wsrcl[i];
  const uint4* wsb = wstr + (size_t)dir * (NREG * 1024);
  uint4 wr0[NREG], wr1[NREG];
#pragma unroll
  for (int g = 0; g < NREG; ++g) {
    wr0[g] = wsb[g * 1024 + t];
    wr1[g] = wsb[g * 1024 + t + 512];
  }
  if (t < 32) hpk4[t] = uint4{0, 0, 0, 0};
  __syncthreads();

  const float* xgbase =
      xg + (size_t)(dir * (BB * TT_LEN) + b * TT_LEN) * G4 + t;
  float wo = (t < HH) ? w_out[dir * HH + t] : 0.0f;
  float cstate = 0.0f;

  int t0 = dir ? (TT_LEN - 1) : 0;
  float xgn0 = xgbase[(size_t)t0 * G4];
  float xgn1 = xgbase[(size_t)t0 * G4 + 512];

#pragma unroll 1
  for (int s = 0; s < TT_LEN; ++s) {
    int tt = dir ? (TT_LEN - 1 - s) : s;
    float acc0a = xgn0, acc1a = xgn1;
    float acc0b = 0.0f, acc1b = 0.0f;
    if (s + 1 < TT_LEN) {
      int t2 = dir ? (TT_LEN - 2 - s) : (s + 1);
      xgn0 = xgbase[(size_t)t2 * G4];
      xgn1 = xgbase[(size_t)t2 * G4 + 512];
    }
#pragma unroll
    for (int c = 0; c < NCH_L2; ++c) {
      uint4 h = hpk4[c];
      uint4 w0 = wlds[c * 1024 + t];
      uint4 w1 = wlds[c * 1024 + 512 + t];
      acc0a = dot2acc(w0.x, h.x, acc0a);
      acc0a = dot2acc(w0.y, h.y, acc0a);
      acc0a = dot2acc(w0.z, h.z, acc0a);
      acc0a = dot2acc(w0.w, h.w, acc0a);
      acc1a = dot2acc(w1.x, h.x, acc1a);
      acc1a = dot2acc(w1.y, h.y, acc1a);
      acc1a = dot2acc(w1.z, h.z, acc1a);
      acc1a = dot2acc(w1.w, h.w, acc1a);
    }
#pragma unroll
    for (int g = 0; g < NREG; ++g) {
      uint4 h = hpk4[NCH_L2 + g];
      if (g < 12) {
        acc0a = dot2acc(wr0[g].x, h.x, acc0a);
        acc0a = dot2acc(wr0[g].y, h.y, acc0a);
        acc0a = dot2acc(wr0[g].z, h.z, acc0a);
        acc0a = dot2acc(wr0[g].w, h.w, acc0a);
        acc1a = dot2acc(wr1[g].x, h.x, acc1a);
        acc1a = dot2acc(wr1[g].y, h.y, acc1a);
        acc1a = dot2acc(wr1[g].z, h.z, acc1a);
        acc1a = dot2acc(wr1[g].w, h.w, acc1a);
      } else {
        acc0b = dot2acc(wr0[g].x, h.x, acc0b);
        acc0b = dot2acc(wr0[g].y, h.y, acc0b);
        acc0b = dot2acc(wr0[g].z, h.z, acc0b);
        acc0b = dot2acc(wr0[g].w, h.w, acc0b);
        acc1b = dot2acc(wr1[g].x, h.x, acc1b);
        acc1b = dot2acc(wr1[g].y, h.y, acc1b);
        acc1b = dot2acc(wr1[g].z, h.z, acc1b);
        acc1b = dot2acc(wr1[g].w, h.w, acc1b);
      }
    }
    gates[t] = acc0a + acc0b;
    gates[512 + t] = acc1a + acc1b;
    __syncthreads();

    if (t < HH) {
      float4 g4 = ((const float4*)gates)[t];
      float ig = sigm(g4.x);
      float fg = sigm(g4.y);
      float gg = tanhf(g4.z);
      float og = sigm(g4.w);
      cstate = fg * cstate + ig * gg;
      float h = og * tanhf(cstate);
      float prod = h * wo;
#pragma unroll
      for (int off = 32; off > 0; off >>= 1) prod += __shfl_down(prod, off, 64);
      if (lane == 0) wpart[s & 1][wid] = prod;
      float hn = __shfl_down(h, 1, 64);
      if (!(t & 1)) ((unsigned int*)hpk4)[t >> 1] = packh(h, hn);
    }
    __syncthreads();
    if (t == 0) {
      scores_part[(size_t)(dir * BB + b) * TT_LEN + tt] =
          wpart[s & 1][0] + wpart[s & 1][1] + wpart[s & 1][2] + wpart[s & 1][3];
    }
  }
}

// ---------------- K4: CRF fwd+bwd in PARALLEL WAVES ------------------------
// 32 blocks x 128 threads. Wave 0: forward alpha -> ast rows + logZ -> lzv.
// Wave 1: backward beta0 -> bst rows (beta never reads alpha!). Marginals
// joined in the separate fully-parallel `marg` kernel. Inner loops unroll 4
// to rotate registers (breaks per-step store-WAR vmcnt stalls). No loads in
// either recurrence loop.
__global__ __launch_bounds__(128) void dp3(const float* __restrict__ scores_part,
                                           const float* __restrict__ b_out,
                                           float* __restrict__ ast_g,
                                           float* __restrict__ bst_g,
                                           float* __restrict__ lzv) {
  int b = blockIdx.x;
  int l = threadIdx.x & 63;
  int w = threadIdx.x >> 6;
  const float* spf = scores_part + (size_t)b * TT_LEN;
  const float* spb = scores_part + (size_t)(BB + b) * TT_LEN;
  float bo = b_out[0];

  float ur[8];
#pragma unroll
  for (int i = 0; i < 8; ++i)
    ur[i] = (spf[i * 64 + l] + spb[i * 64 + l] + bo) * INV_TEMP;

  if (w == 0) {
    // ---------------- forward ----------------
    float* ast = ast_g + (size_t)b * TT_LEN * AST_STRIDE;
    int lm1 = (l + 63) & 63;
    float a0[3], a1[3];
    float u00 = __shfl(ur[0], 0, 64);
    a0[0] = (l == 1) ? (u00 + TRANS_T) : NEGF;
    a0[1] = NEGF;
    a0[2] = NEGF;
    a1[0] = (l == 0) ? 0.0f : NEGF;
    a1[1] = NEGF;
    a1[2] = NEGF;
    ast[l] = a0[0];
    ast[64 + l] = a0[1];
    if (l < 27) ast[128 + l] = a0[2];

#pragma unroll
    for (int ch = 0; ch < 8; ++ch) {
      float uc = ur[ch];
#pragma unroll 4
      for (int tt = (ch == 0 ? 1 : 0); tt < 64; ++tt) {
        int t = ch * 64 + tt;
        float u0t = __shfl(uc, tt, 64);
        float w0a = __shfl(a0[0], lm1, 64);
        float w1a = __shfl(a0[1], lm1, 64);
        float w2a = __shfl(a0[2], lm1, 64);
        float w0b = __shfl(a1[0], lm1, 64);
        float w1b = __shfl(a1[1], lm1, 64);
        float w2b = __shfl(a1[2], lm1, 64);
        float p0a = (l == 0) ? NEGF : w0a;
        float p1a = (l == 0) ? w0a : w1a;
        float p2a = (l == 0) ? w1a : w2a;
        float p0b = (l == 0) ? NEGF : w0b;
        float p1b = (l == 0) ? w0b : w1b;
        float p2b = (l == 0) ? w1b : w2b;
        float n00 = u0t + la(p0a + TRANS_T, p0b);
        float n01 = u0t + la(p1a + TRANS_T, p1b);
        float n02 = u0t + la(p2a + TRANS_T, p2b);
        float n10 = la(a0[0], a1[0]);
        float n11 = la(a0[1], a1[1]);
        float n12 = la(a0[2], a1[2]);
        a0[0] = n00;
        a0[1] = n01;
        a0[2] = (l < 27) ? n02 : NEGF;
        a1[0] = n10;
        a1[1] = n11;
        a1[2] = (l < 27) ? n12 : NEGF;
        float* astr = ast + (size_t)t * AST_STRIDE;
        astr[l] = a0[0];
        astr[64 + l] = a0[1];
        if (l < 27) astr[128 + l] = a0[2];
      }
    }
    // logZ
    float f00 = a0[0] + TRANS_T, f01 = a0[1] + TRANS_T, f02 = a0[2] + TRANS_T;
    float m = fmaxf(fmaxf(fmaxf(f00, f01), fmaxf(f02, a1[0])),
                    fmaxf(a1[1], a1[2]));
#pragma unroll
    for (int off = 32; off > 0; off >>= 1) m = fmaxf(m, __shfl_xor(m, off, 64));
    float es = __expf(f00 - m) + __expf(f01 - m) + __expf(f02 - m) +
               __expf(a1[0] - m) + __expf(a1[1] - m) + __expf(a1[2] - m);
#pragma unroll
    for (int off = 32; off > 0; off >>= 1) es += __shfl_xor(es, off, 64);
    if (l == 0) lzv[b] = m + __logf(es);
  } else {
    // ---------------- backward (independent of alpha) ----------------
    float* bst = bst_g + (size_t)b * TT_LEN * AST_STRIDE;
    int lp1 = (l + 1) & 63;
    float b0[3], b1[3];
    b0[0] = TRANS_T;
    b0[1] = TRANS_T;
    b0[2] = (l < 27) ? TRANS_T : NEGF;
    b1[0] = 0.0f;
    b1[1] = 0.0f;
    b1[2] = (l < 27) ? 0.0f : NEGF;
    // row 511 = init beta0
    {
      float* br = bst + (size_t)(TT_LEN - 1) * AST_STRIDE;
      br[l] = b0[0];
      br[64 + l] = b0[1];
      if (l < 27) br[128 + l] = b0[2];
    }
#pragma unroll
    for (int ch = 7; ch >= 0; --ch) {
      float uc = ur[ch];
#pragma unroll 4
      for (int tt = 63; tt >= (ch == 0 ? 1 : 0); --tt) {
        int t = ch * 64 + tt;
        float u0t = __shfl(uc, tt, 64);
        float w0 = __shfl(b0[0], lp1, 64);
        float w1 = __shfl(b0[1], lp1, 64);
        float w2 = __shfl(b0[2], lp1, 64);
        float x2 = (l == 63) ? NEGF : w2;
        float x1 = (l == 63) ? w2 : w1;
        float x0 = (l == 63) ? w1 : w0;
        float nb00 = la(u0t + TRANS_T + x0, b1[0]);
        float nb01 = la(u0t + TRANS_T + x1, b1[1]);
        float nb02 = la(u0t + TRANS_T + x2, b1[2]);
        float nb10 = la(u0t + x0, b1[0]);
        float nb11 = la(u0t + x1, b1[1]);
        float nb12 = la(u0t + x2, b1[2]);
        b0[0] = nb00;
        b0[1] = nb01;
        b0[2] = (l < 27) ? nb02 : NEGF;
        b1[0] = nb10;
        b1[1] = nb11;
        b1[2] = (l < 27) ? nb12 : NEGF;
        float* br = bst + (size_t)(t - 1) * AST_STRIDE;
        br[l] = b0[0];
        br[64 + l] = b0[1];
        if (l < 27) br[128 + l] = b0[2];
      }
    }
  }
}

// ---------------- K5: marginals, fully parallel ----------------------------
// out[b,t] = sum_c exp(alpha0[c] + beta0[c] - lz). One wave per (b,t) row.
__global__ __launch_bounds__(256) void marg(const float* __restrict__ ast_g,
                                            const float* __restrict__ bst_g,
                                            const float* __restrict__ lzv,
                                            float* __restrict__ out) {
  int row = blockIdx.x * 4 + (threadIdx.x >> 6);
  int l = threadIdx.x & 63;
  int b = row >> 9;
  const float* ar = ast_g + (size_t)row * AST_STRIDE;
  const float* br = bst_g + (size_t)row * AST_STRIDE;
  float lz = lzv[b];
  float s = __expf(ar[l] + br[l] - lz) + __expf(ar[64 + l] + br[64 + l] - lz) +
            ((l < 27) ? __expf(ar[128 + l] + br[128 + l] - lz) : 0.0f);
#pragma unroll
  for (int off = 32; off > 0; off >>= 1) s += __shfl_xor(s, off, 64);
  if (l == 0) out[row] = s;
}

// ---------------------------------------------------------------------------
extern "C" void kernel_launch(void* const* d_in, const int* in_sizes, int n_in,
                              void* d_out, int out_size, void* d_ws, size_t ws_size,
                              hipStream_t stream) {
  const int* x = (const int*)d_in[0];
  const float* embed = (const float*)d_in[3];
  const float* wi_f = (const float*)d_in[4];
  const float* wh_f = (const float*)d_in[5];
  const float* bf = (const float*)d_in[6];
  const float* wi_b = (const float*)d_in[7];
  const float* wh_b = (const float*)d_in[8];
  const float* bbias = (const float*)d_in[9];
  const float* w_out = (const float*)d_in[10];
  const float* b_out = (const float*)d_in[11];

  float* ws = (float*)d_ws;
  float* b_p = ws;                                      // 2048 f32
  unsigned int* wlds_h = (unsigned int*)(b_p + 2 * G4); // 65536 dw
  unsigned int* wstr_h = wlds_h + 2 * NCH_L2 * 4096;    // 196608 dw
  unsigned int* wi_frag = wstr_h + 2 * NREG * 4096;     // 327680 dw
  uint4* emb_frag = (uint4*)(wi_frag + 2 * 64 * 10 * 64 * 4);  // 655360 uint4
  // bst aliases emb_frag (dead after xg_mfma): 32*512*159 f32 = 10.42 MB
  // fits inside emb_frag's 10.49 MB.
  float* bst_g = (float*)emb_frag;
  float* xg = (float*)(emb_frag + (size_t)1024 * 10 * 64);     // 33554432 f32
  float* scores_part = xg + (size_t)2 * BB * TT_LEN * G4;      // 32768 f32
  float* lzv = scores_part + 2 * BB * TT_LEN;           // 32 f32 (+pad 32)
  float* ast_g = lzv + 64;                              // 32*512*159 f32
  float* outp = (float*)d_out;

  prep_weights<<<256, 256, 0, stream>>>(wi_f, wi_b, wh_f, wh_b, bf, bbias,
                                        wi_frag, b_p, wlds_h, wstr_h);
  gather_emb<<<(BB * TT_LEN) / 16, 256, 0, stream>>>(x, embed, emb_frag);
  dim3 g1(16, 256, 2);
  xg_mfma<<<g1, 256, 0, stream>>>(emb_frag, (const uint4*)wi_frag, b_p, xg);
  lstm_ck<<<64, 512, 0, stream>>>(xg, wlds_h, (const uint4*)wstr_h, w_out,
                                  scores_part);
  dp3<<<BB, 128, 0, stream>>>(scores_part, b_out, ast_g, bst_g, lzv);
  marg<<<(BB * TT_LEN) / 4, 256, 0, stream>>>(ast_g, bst_g, lzv, outp);
}